// Round 10
// baseline (528.985 us; speedup 1.0000x reference)
//
#include <hip/hip_runtime.h>
#include <math.h>

#define B_ 2
#define S_ 2048
#define D_ 768
#define H_ 12
#define HD_ 64
#define KKEEP 614            // max(1, int(0.3*2048))
#define M_ (B_*S_)           // 4096
#define KD_ 768
#define SRW 2072             // scB row stride in ushorts (4144B rows, 16B aligned)
#define TQ 8                 // q rows per attention block

typedef __attribute__((ext_vector_type(8))) short bf8;   // 8 bf16 = 4 VGPR (MFMA A/B frag)
typedef __attribute__((ext_vector_type(4))) float f4;    // MFMA 16x16 C/D frag

__device__ __forceinline__ unsigned short f2bf(float f) {   // RNE fp32->bf16
    unsigned u = __float_as_uint(f);
    u += 0x7FFF + ((u >> 16) & 1);
    return (unsigned short)(u >> 16);
}
__device__ __forceinline__ float bf2f(unsigned short h) {
    return __uint_as_float((unsigned)h << 16);
}
// fp32 -> orderable-u16 (bf16-RNE in orderable space)
__device__ __forceinline__ unsigned f2ord16(float f) {
    unsigned u = __float_as_uint(f);
    unsigned o32 = u ^ ((unsigned)((int)u >> 31) | 0x80000000u);
    return (o32 + 0x7FFFu + ((o32 >> 16) & 1u)) >> 16;
}
// orderable-u16 -> fp32 (exact bf16 value)
__device__ __forceinline__ float ord16_to_f(unsigned o16) {
    unsigned o = o16 << 16;
    unsigned mask = 0x80000000u | ~(unsigned)((int)o >> 31);
    return __uint_as_float((o ^ mask) & 0xFFFF0000u);
}
// async 16B global->LDS DMA; LDS dest wave-contiguous (base + laneidx*16B)
__device__ __forceinline__ void gl_lds16(const unsigned short* g, unsigned short* l) {
    __builtin_amdgcn_global_load_lds(
        (const __attribute__((address_space(1))) void*)g,
        (__attribute__((address_space(3))) void*)l, 16, 0, 0);
}

// One launch: x -> hi+lo planes; 4 weight mats -> hi plane ONLY (2-pass GEMMs
// never read W-lo: dropped ah*bl term is ~2^-9 rel, below the bf16 rounding
// already applied to K/V/score paths).
__global__ void split_all(const float* __restrict__ x,
                          const float* __restrict__ w0, const float* __restrict__ w1,
                          const float* __restrict__ w2, const float* __restrict__ w3,
                          unsigned short* __restrict__ xhi, unsigned short* __restrict__ xlo,
                          unsigned short* __restrict__ whi) {
    const int NPc = M_ * D_;
    const int NWc = D_ * D_;
    int i = blockIdx.x * blockDim.x + threadIdx.x;
    if (i < NPc) {
        float f = x[i];
        unsigned short h = f2bf(f);
        xhi[i] = h;
        xlo[i] = f2bf(f - bf2f(h));
    } else {
        int j = i - NPc;
        int which = j / NWc;
        int k = j - which * NWc;
        const float* src = which == 0 ? w0 : which == 1 ? w1 : which == 2 ? w2 : w3;
        whi[j] = f2bf(src[k]);
    }
}

// Fused Q/K/V projection, 2-pass split ((ah+al)*bh): C = x @ Wcat^T + bias.
// Tile 128(M) x 64(N); grid.y in [0,36): which = y/12.
//   which 0 (Q): BHSD hi+lo, pre-scaled 0.125   which 1 (K): BHSD hi
//   which 2 (V): BHDS hi
__global__ __launch_bounds__(256)
void gemm_qkv(const unsigned short* __restrict__ Ahi, const unsigned short* __restrict__ Alo,
              const unsigned short* __restrict__ Wch,
              const float* __restrict__ bq, const float* __restrict__ bk,
              const float* __restrict__ bv,
              unsigned short* __restrict__ Qh, unsigned short* __restrict__ Ql,
              unsigned short* __restrict__ Kh, unsigned short* __restrict__ Vth) {
    __shared__ __align__(16) unsigned short Ah[128][32], Al[128][32], Bh[64][32];  // 20KB
    const int bm = blockIdx.x * 128, bnG = blockIdx.y * 64;
    const int which = blockIdx.y / 12;                  // 0=Q 1=K 2=V
    const int bn = bnG - which * 768;                   // local col tile base
    const float* bias = which == 0 ? bq : (which == 1 ? bk : bv);
    const int tid = threadIdx.x, lane = tid & 63, wave = tid >> 6;
    const int col = lane & 15, quad = lane >> 4;

    f4 acc[2][4];
#pragma unroll
    for (int mi = 0; mi < 2; ++mi)
#pragma unroll
        for (int ni = 0; ni < 4; ++ni) { f4 z = {0.f,0.f,0.f,0.f}; acc[mi][ni] = z; }

    for (int kt = 0; kt < KD_; kt += 32) {
        __syncthreads();
#pragma unroll
        for (int c = 0; c < 2; ++c) {
            int idx = c * 256 + tid;
            int row = idx >> 2, ko = (idx & 3) * 8;
            gl_lds16(&Ahi[(size_t)(bm + row) * KD_ + kt + ko], &Ah[0][0] + idx * 8);
            gl_lds16(&Alo[(size_t)(bm + row) * KD_ + kt + ko], &Al[0][0] + idx * 8);
        }
        {
            int row = tid >> 2, ko = (tid & 3) * 8;
            gl_lds16(&Wch[(size_t)(bnG + row) * KD_ + kt + ko], &Bh[0][0] + tid * 8);
        }
        __syncthreads();   // drains vmcnt incl. global_load_lds

        bf8 af[2][2], wf[4];
#pragma unroll
        for (int mi = 0; mi < 2; ++mi) {
            int r = wave * 32 + mi * 16 + col;
            af[mi][0] = *(const bf8*)&Ah[r][quad * 8];
            af[mi][1] = *(const bf8*)&Al[r][quad * 8];
        }
#pragma unroll
        for (int ni = 0; ni < 4; ++ni)
            wf[ni] = *(const bf8*)&Bh[ni * 16 + col][quad * 8];
#pragma unroll
        for (int mi = 0; mi < 2; ++mi)
#pragma unroll
            for (int ni = 0; ni < 4; ++ni) {
                acc[mi][ni] = __builtin_amdgcn_mfma_f32_16x16x32_bf16(af[mi][0], wf[ni], acc[mi][ni], 0, 0, 0);
                acc[mi][ni] = __builtin_amdgcn_mfma_f32_16x16x32_bf16(af[mi][1], wf[ni], acc[mi][ni], 0, 0, 0);
            }
    }

    float bvv[4];
#pragma unroll
    for (int ni = 0; ni < 4; ++ni) bvv[ni] = bias[bn + ni * 16 + col];
#pragma unroll
    for (int mi = 0; mi < 2; ++mi)
#pragma unroll
        for (int ni = 0; ni < 4; ++ni)
#pragma unroll
            for (int r = 0; r < 4; ++r) {
                int m = bm + wave * 32 + mi * 16 + quad * 4 + r;  // C row = quad*4+reg
                int n = bn + ni * 16 + col;                       // C col = lane&15
                float v = acc[mi][ni][r] + bvv[ni];
                if (which == 0) v *= 0.125f;                      // fold 1/sqrt(64)
                int b = m >> 11, s = m & 2047, h = n >> 6, d = n & 63;
                unsigned short hh = f2bf(v);
                if (which == 0) {
                    size_t idx = (((size_t)b * H_ + h) * S_ + s) * HD_ + d;
                    Qh[idx] = hh;
                    Ql[idx] = f2bf(v - bf2f(hh));
                } else if (which == 1) {
                    Kh[(((size_t)b * H_ + h) * S_ + s) * HD_ + d] = hh;
                } else {
                    Vth[(((size_t)b * H_ + h) * HD_ + d) * S_ + s] = hh;
                }
            }
}

// O-projection, 2-pass split: fp32 out = AO @ Wo^T + bo
__global__ __launch_bounds__(256)
void gemm_o(const unsigned short* __restrict__ Ahi, const unsigned short* __restrict__ Alo,
            const unsigned short* __restrict__ Whi,
            const float* __restrict__ bias, float* __restrict__ outf) {
    __shared__ __align__(16) unsigned short Ah[128][32], Al[128][32], Bh[64][32];
    const int bm = blockIdx.x * 128, bn = blockIdx.y * 64;
    const int tid = threadIdx.x, lane = tid & 63, wave = tid >> 6;
    const int col = lane & 15, quad = lane >> 4;

    f4 acc[2][4];
#pragma unroll
    for (int mi = 0; mi < 2; ++mi)
#pragma unroll
        for (int ni = 0; ni < 4; ++ni) { f4 z = {0.f,0.f,0.f,0.f}; acc[mi][ni] = z; }

    for (int kt = 0; kt < KD_; kt += 32) {
        __syncthreads();
#pragma unroll
        for (int c = 0; c < 2; ++c) {
            int idx = c * 256 + tid;
            int row = idx >> 2, ko = (idx & 3) * 8;
            gl_lds16(&Ahi[(size_t)(bm + row) * KD_ + kt + ko], &Ah[0][0] + idx * 8);
            gl_lds16(&Alo[(size_t)(bm + row) * KD_ + kt + ko], &Al[0][0] + idx * 8);
        }
        {
            int row = tid >> 2, ko = (tid & 3) * 8;
            gl_lds16(&Whi[(size_t)(bn + row) * KD_ + kt + ko], &Bh[0][0] + tid * 8);
        }
        __syncthreads();

        bf8 af[2][2], wf[4];
#pragma unroll
        for (int mi = 0; mi < 2; ++mi) {
            int r = wave * 32 + mi * 16 + col;
            af[mi][0] = *(const bf8*)&Ah[r][quad * 8];
            af[mi][1] = *(const bf8*)&Al[r][quad * 8];
        }
#pragma unroll
        for (int ni = 0; ni < 4; ++ni)
            wf[ni] = *(const bf8*)&Bh[ni * 16 + col][quad * 8];
#pragma unroll
        for (int mi = 0; mi < 2; ++mi)
#pragma unroll
            for (int ni = 0; ni < 4; ++ni) {
                acc[mi][ni] = __builtin_amdgcn_mfma_f32_16x16x32_bf16(af[mi][0], wf[ni], acc[mi][ni], 0, 0, 0);
                acc[mi][ni] = __builtin_amdgcn_mfma_f32_16x16x32_bf16(af[mi][1], wf[ni], acc[mi][ni], 0, 0, 0);
            }
    }

    float bvv[4];
#pragma unroll
    for (int ni = 0; ni < 4; ++ni) bvv[ni] = bias[bn + ni * 16 + col];
#pragma unroll
    for (int mi = 0; mi < 2; ++mi)
#pragma unroll
        for (int ni = 0; ni < 4; ++ni)
#pragma unroll
            for (int r = 0; r < 4; ++r) {
                int m = bm + wave * 32 + mi * 16 + quad * 4 + r;
                int n = bn + ni * 16 + col;
                outf[(size_t)m * D_ + n] = acc[mi][ni][r] + bvv[ni];
            }
}

// Attention: block = TQ=8 q rows of one (b,h); 512 thr = 8 waves; wave owns 256
// keys in QK and one full row in selection. 33.2KB LDS -> 4 blocks/CU: phases of
// independent blocks overlap (QK-MFMA / selection-VALU / PV-VMEM co-scheduled),
// barriers sync only 8 waves. MFMA A-frag rows 8-15 are duplicates (m=16 tile,
// 8 q rows) -- discarded at the C side; MFMA pipe is ~6% busy so the waste is free.
__global__ __launch_bounds__(512, 8)
void attn_kernel(const unsigned short* __restrict__ Qhi, const unsigned short* __restrict__ Qlo,
                 const unsigned short* __restrict__ Khi,
                 const unsigned short* __restrict__ Vthi,
                 unsigned short* __restrict__ AOhi, unsigned short* __restrict__ AOlo) {
    const int bid = blockIdx.x;            // 6144 = 24 bh * 256 q-tiles
    const int xcd = bid & 7, sub = (bid >> 3) % 3, tile = bid / 24;
    const int bh = xcd * 3 + sub;          // L2 locality: 3 (b,h) per XCD
    const int b = bh / H_, h = bh % H_;
    const int q0 = tile * TQ;
    const int tid = threadIdx.x, lane = tid & 63, wave = tid >> 6;   // wave 0..7
    const int col = lane & 15, quad = lane >> 4;

    __shared__ __align__(16) unsigned char arena[TQ * 4144];   // 33.2KB
    unsigned short* scB = (unsigned short*)arena;              // [8][SRW] u16
    float (*osum)[TQ][64] = (float (*)[TQ][64])arena;          // [8][8][64] f32 (16KB alias)
    __shared__ float linv[TQ];

    // Q A-frags: m = col -> q row (col&7); rows 8-15 duplicate rows 0-7
    const size_t qbase = ((size_t)bh * S_ + q0 + (col & 7)) * HD_;
    bf8 qh0 = *(const bf8*)&Qhi[qbase + quad * 8];
    bf8 qh1 = *(const bf8*)&Qhi[qbase + 32 + quad * 8];
    bf8 ql0 = *(const bf8*)&Qlo[qbase + quad * 8];
    bf8 ql1 = *(const bf8*)&Qlo[qbase + 32 + quad * 8];

    // ---- QK^T (4-MFMA split): wave covers keys [wave*256, wave*256+256) ----
    const size_t kbb = (size_t)bh * S_ * HD_;
#pragma unroll 1
    for (int t = 0; t < 16; ++t) {
        const int key = wave * 256 + t * 16 + col;
        const size_t kr = kbb + (size_t)key * HD_;
        bf8 kh0 = *(const bf8*)&Khi[kr + quad * 8];
        bf8 kh1 = *(const bf8*)&Khi[kr + 32 + quad * 8];
        f4 a = {0.f, 0.f, 0.f, 0.f};
        a = __builtin_amdgcn_mfma_f32_16x16x32_bf16(qh0, kh0, a, 0, 0, 0);
        a = __builtin_amdgcn_mfma_f32_16x16x32_bf16(qh1, kh1, a, 0, 0, 0);
        a = __builtin_amdgcn_mfma_f32_16x16x32_bf16(ql0, kh0, a, 0, 0, 0);
        a = __builtin_amdgcn_mfma_f32_16x16x32_bf16(ql1, kh1, a, 0, 0, 0);
        if (quad < 2) {                     // C rows 0..7 are the real q rows
#pragma unroll
            for (int r = 0; r < 4; ++r)
                scB[(quad * 4 + r) * SRW + key] = (unsigned short)f2ord16(a[r]);
        }
    }
    __syncthreads();                                       // [1] transpose visible

    // ---- wave w owns row w: kv[16] packed dwords + pre-shifted kvs[16] ----
    unsigned* rowp = (unsigned*)(arena + wave * 4144);
    unsigned kv[16], kvs[16];
#pragma unroll
    for (int j = 0; j < 16; ++j) kv[j] = rowp[lane + 64 * j];   // conflict-free
#pragma unroll
    for (int j = 0; j < 16; ++j) kvs[j] = kv[j] << 16;

    // row max (lexicographic dominance on packed halves)
    unsigned Mhi = 0, Mlo = 0;
#pragma unroll
    for (int j = 0; j < 16; ++j) {
        Mhi = kv[j]  > Mhi ? kv[j]  : Mhi;
        Mlo = kvs[j] > Mlo ? kvs[j] : Mlo;
    }
    unsigned mo = (Mhi >> 16) > (Mlo >> 16) ? (Mhi >> 16) : (Mlo >> 16);
#pragma unroll
    for (int off = 1; off < 64; off <<= 1) {
        unsigned v = __shfl_xor((int)mo, off, 64);
        mo = mo > v ? mo : v;
    }

    // ---- threshold: largest T with count(>=T) >= KKEEP; ballot+popcount ----
    unsigned T = 0;
#pragma unroll 1
    for (int bit = 15; bit >= 0; --bit) {
        unsigned candh = (T | (1u << bit)) << 16;
        int cnt = 0;
#pragma unroll
        for (int j = 0; j < 16; ++j) {
            cnt += __popcll(__ballot(kv[j]  >= candh));    // hi halves
            cnt += __popcll(__ballot(kvs[j] >= candh));    // lo halves
        }
        if (cnt >= KKEEP) {
            T |= (1u << bit);
            if (cnt == KKEEP) break;       // set {k>=T} already final
        }
    }

    // ---- weights: w = exp2(fma(s,log2e,-m*log2e)) if key >= T else 0 ----
    const float L2E = 1.44269504f;
    const float mb = ord16_to_f(mo) * L2E;
    float ls = 0.f;
#pragma unroll 1
    for (int j = 0; j < 16; ++j) {
        unsigned lo16 = kv[j] & 0xFFFFu;
        unsigned hi16 = kv[j] >> 16;
        float wl = __builtin_amdgcn_exp2f(__builtin_fmaf(ord16_to_f(lo16), L2E, -mb));
        float wh = __builtin_amdgcn_exp2f(__builtin_fmaf(ord16_to_f(hi16), L2E, -mb));
        wl = (lo16 >= T) ? wl : 0.f;
        wh = (hi16 >= T) ? wh : 0.f;
        ls += wl + wh;
        rowp[lane + 64 * j] = (unsigned)f2bf(wl) | ((unsigned)f2bf(wh) << 16);
    }
#pragma unroll
    for (int off = 1; off < 64; off <<= 1) ls += __shfl_xor(ls, off, 64);
    if (lane == 0) linv[wave] = 1.f / ls;
    __syncthreads();                                       // [2] weights + linv visible

    // ---- PV: A-frags (P rows col&7, dup for col>=8) from scB; V^T from global ----
    f4 od[4];
#pragma unroll
    for (int dt = 0; dt < 4; ++dt) { f4 z = {0.f,0.f,0.f,0.f}; od[dt] = z; }
    const size_t vbb = (size_t)bh * HD_ * S_;
#pragma unroll 1
    for (int c = 0; c < 8; ++c) {
        const int sbase = wave * 256 + c * 32 + quad * 8;
        bf8 ph = *(const bf8*)&scB[(col & 7) * SRW + sbase];
#pragma unroll
        for (int dt = 0; dt < 4; ++dt) {
            bf8 vh = *(const bf8*)&Vthi[vbb + (size_t)(dt * 16 + col) * S_ + sbase];
            od[dt] = __builtin_amdgcn_mfma_f32_16x16x32_bf16(ph, vh, od[dt], 0, 0, 0);
        }
    }
    __syncthreads();                                       // [3] all scB reads done
    if (quad < 2) {                                        // C rows 0..7 valid
#pragma unroll
        for (int dt = 0; dt < 4; ++dt)
#pragma unroll
            for (int r = 0; r < 4; ++r)
                osum[wave][quad * 4 + r][dt * 16 + col] = od[dt][r];
    }
    __syncthreads();                                       // [4] partials visible

    // ---- final: 512 threads cover 8x64 (q,d); sum 8 partials, emit planes ----
    {
        int q = tid >> 6, d = tid & 63;
        float s = 0.f;
#pragma unroll
        for (int w = 0; w < 8; ++w) s += osum[w][q][d];
        s *= linv[q];
        size_t idx = ((size_t)b * S_ + q0 + q) * D_ + h * HD_ + d;
        unsigned short hh = f2bf(s);
        AOhi[idx] = hh;
        AOlo[idx] = f2bf(s - bf2f(hh));
    }
}

extern "C" void kernel_launch(void* const* d_in, const int* in_sizes, int n_in,
                              void* d_out, int out_size, void* d_ws, size_t ws_size,
                              hipStream_t stream) {
    const float* x  = (const float*)d_in[0];
    const float* Wq = (const float*)d_in[1];
    const float* bq = (const float*)d_in[2];
    const float* Wk = (const float*)d_in[3];
    const float* bk = (const float*)d_in[4];
    const float* Wv = (const float*)d_in[5];
    const float* bv = (const float*)d_in[6];
    const float* Wo = (const float*)d_in[7];
    const float* bo = (const float*)d_in[8];
    float* out = (float*)d_out;

    const size_t NP = (size_t)M_ * D_;      // 3,145,728 elems
    const size_t NW = (size_t)D_ * D_;      // 589,824 elems
    unsigned short* p = (unsigned short*)d_ws;
    unsigned short* xhi = p;  p += NP;
    unsigned short* xlo = p;  p += NP;
    unsigned short* Wch = p;  p += 4 * NW;   // concatenated [Wq|Wk|Wv|Wo] hi
    unsigned short* Qh  = p;  p += NP;  unsigned short* Ql  = p;  p += NP;
    unsigned short* Kh  = p;  p += NP;
    unsigned short* Vth = p;  p += NP;
    // AO planes alias x planes (x dead after the projections)
    unsigned short* AOh = xhi;
    unsigned short* AOl = xlo;

    {
        int total = (int)(NP + 4 * NW);      // 5,505,024 (multiple of 256)
        split_all<<<total / 256, 256, 0, stream>>>(x, Wq, Wk, Wv, Wo, xhi, xlo, Wch);
    }

    {
        dim3 g(M_ / 128, 36);               // 3 x 768/64 column tiles
        gemm_qkv<<<g, 256, 0, stream>>>(xhi, xlo, Wch, bq, bk, bv, Qh, Ql, Kh, Vth);
    }

    attn_kernel<<<(S_ / TQ) * B_ * H_, 512, 0, stream>>>(Qh, Ql, Kh, Vth, AOh, AOl);

    {
        dim3 g(M_ / 128, D_ / 64);
        gemm_o<<<g, 256, 0, stream>>>(AOh, AOl, Wch + 3 * NW, bo, out);
    }
}